// Round 1
// baseline (373.214 us; speedup 1.0000x reference)
//
#include <hip/hip_runtime.h>
#include <hip/hip_bf16.h>

// Problem geometry (QuantizedLinear): out = x @ W^T + bias
//   x: [4,2048,4096] f32  -> M=8192, K=4096
//   codes: [NOG=4096][NIG=512][NCB=1] int32
//   codebooks: [1][65536][1][8] f32   (2 MB, L2-resident)
//   scales: [4096] f32 (per output channel), bias: [4096] f32
//   W[n,k] = cb[codes[n, k/8]][k%8] * scales[n]   (scale folded into epilogue)
#define M_DIM 8192
#define N_DIM 4096
#define K_DIM 4096
#define NOG 4096
#define NIG 512

typedef __bf16 bf16x8 __attribute__((ext_vector_type(8)));
typedef float f32x4 __attribute__((ext_vector_type(4)));
typedef short short8 __attribute__((ext_vector_type(8)));

typedef const __attribute__((address_space(1))) void* as1_cvoid_p;
typedef __attribute__((address_space(3))) void* as3_void_p;

// round-to-nearest-even f32 -> bf16 (inputs are finite/normal)
__device__ __forceinline__ unsigned short f2bf(float f) {
  union { float f; unsigned u; } c; c.f = f;
  unsigned u = c.u;
  return (unsigned short)((u + 0x7fffu + ((u >> 16) & 1u)) >> 16);
}

// ---- Kernel 1: x f32 -> bf16, vectorized (2x float4 in, 16B out per iter)
__global__ __launch_bounds__(256) void cvt_x_kernel(const float* __restrict__ x,
                                                    unsigned short* __restrict__ xb,
                                                    int n8) {
  int i = blockIdx.x * blockDim.x + threadIdx.x;
  int stride = gridDim.x * blockDim.x;
  for (; i < n8; i += stride) {
    const float4* p = (const float4*)(x) + (size_t)i * 2;
    float4 a = p[0], b = p[1];
    short8 o;
    o[0] = (short)f2bf(a.x); o[1] = (short)f2bf(a.y);
    o[2] = (short)f2bf(a.z); o[3] = (short)f2bf(a.w);
    o[4] = (short)f2bf(b.x); o[5] = (short)f2bf(b.y);
    o[6] = (short)f2bf(b.z); o[7] = (short)f2bf(b.w);
    ((short8*)xb)[i] = o;
  }
}

// ---- Kernel 2: dequant gather -> bf16 W stored [N][K] (B^T layout, row n contiguous in k)
__global__ __launch_bounds__(256) void dequant_kernel(const int* __restrict__ codes,
                                                      const float* __restrict__ cb,
                                                      unsigned short* __restrict__ wb) {
  int idx = blockIdx.x * blockDim.x + threadIdx.x;   // n*NIG + ig, grid sized exactly
  int code = codes[idx];
  const float4* p = (const float4*)(cb + (size_t)code * 8);
  float4 a = p[0], b = p[1];
  short8 o;
  o[0] = (short)f2bf(a.x); o[1] = (short)f2bf(a.y);
  o[2] = (short)f2bf(a.z); o[3] = (short)f2bf(a.w);
  o[4] = (short)f2bf(b.x); o[5] = (short)f2bf(b.y);
  o[6] = (short)f2bf(b.z); o[7] = (short)f2bf(b.w);
  ((short8*)wb)[idx] = o;   // W[n][ig*8 .. ig*8+7]
}

// ---- Kernel 3: bf16 MFMA GEMM, m97 structure (128x128 tile, BK=32, 4 waves 2x2,
//      4x4 frags of 16x16x32, global_load_lds width=16, fp32 epilogue w/ scale+bias)
__global__ __launch_bounds__(256) void gemm_kernel(
    const unsigned short* __restrict__ A,   // bf16 bits [M][K]
    const unsigned short* __restrict__ B,   // bf16 bits [N][K]
    const float* __restrict__ scales,       // [N]
    const float* __restrict__ bias,         // [N]
    float* __restrict__ C) {                // [M][N]
  constexpr int BM = 128, BN = 128, BK = 32;
  __shared__ __align__(16) unsigned short As[BM * BK];  // 8 KB, rows of 32 bf16 (64B)
  __shared__ __align__(16) unsigned short Bs[BN * BK];  // 8 KB

  const int nbn = N_DIM / BN;          // 32
  const int nwg = gridDim.x;           // 2048 (divisible by 8 -> simple bijective swizzle)
  const int cpx = nwg >> 3;
  const int bid = blockIdx.x;
  const int swz = (bid & 7) * cpx + (bid >> 3);
  const int bm = swz / nbn;
  const int bn = swz % nbn;

  const int tid = threadIdx.x;
  const int w  = tid >> 6;   // wave 0..3
  const int l  = tid & 63;
  const int wr = w >> 1;     // wave row 0..1 (owns 64 output rows)
  const int wc = w & 1;      // wave col 0..1 (owns 64 output cols)

  // staging geometry: wave w issue i writes LDS bytes [(w*2+i)*1024, +1024)
  // linear byte off -> row = off/64, elem col = (off%64)/2
  const int srow_l = l >> 2;          // 0..15
  const int scol   = (l & 3) * 8;     // element col chunk: 0/8/16/24

  const size_t a_row0 = (size_t)bm * BM;
  const size_t b_row0 = (size_t)bn * BN;

  f32x4 acc[4][4];
#pragma unroll
  for (int m = 0; m < 4; ++m)
#pragma unroll
    for (int n = 0; n < 4; ++n) acc[m][n] = (f32x4){0.f, 0.f, 0.f, 0.f};

  for (int kt = 0; kt < K_DIM; kt += BK) {
    __syncthreads();  // previous compute done before overwriting LDS
#pragma unroll
    for (int i = 0; i < 2; ++i) {
      const int rr = (w * 2 + i) * 16 + srow_l;
      const unsigned short* gpa = A + (a_row0 + rr) * K_DIM + kt + scol;
      const unsigned short* gpb = B + (b_row0 + rr) * K_DIM + kt + scol;
      __builtin_amdgcn_global_load_lds((as1_cvoid_p)gpa,
                                       (as3_void_p)((char*)As + (w * 2 + i) * 1024),
                                       16, 0, 0);
      __builtin_amdgcn_global_load_lds((as1_cvoid_p)gpb,
                                       (as3_void_p)((char*)Bs + (w * 2 + i) * 1024),
                                       16, 0, 0);
    }
    __syncthreads();  // staging visible (compiler drains vmcnt before barrier)

    bf16x8 af[4], bfr[4];
    const int koff = (l >> 4) * 8;  // lane's K-chunk within BK=32
#pragma unroll
    for (int m = 0; m < 4; ++m)
      af[m] = *(const bf16x8*)(As + (wr * 64 + m * 16 + (l & 15)) * BK + koff);
#pragma unroll
    for (int n = 0; n < 4; ++n)
      bfr[n] = *(const bf16x8*)(Bs + (wc * 64 + n * 16 + (l & 15)) * BK + koff);

#pragma unroll
    for (int m = 0; m < 4; ++m)
#pragma unroll
      for (int n = 0; n < 4; ++n)
        acc[m][n] = __builtin_amdgcn_mfma_f32_16x16x32_bf16(af[m], bfr[n], acc[m][n], 0, 0, 0);
  }

  // epilogue: out[m,n] = acc * scales[n] + bias[n]
  // C/D layout (16x16x32): col = lane&15, row = (lane>>4)*4 + reg
  const int col_base = bn * BN + wc * 64;
  const int row_base = bm * BM + wr * 64 + ((l >> 4) << 2);
#pragma unroll
  for (int n = 0; n < 4; ++n) {
    const int col = col_base + n * 16 + (l & 15);
    const float s  = scales[col];
    const float bv = bias[col];
#pragma unroll
    for (int m = 0; m < 4; ++m) {
      const int row0 = row_base + m * 16;
      f32x4 v = acc[m][n];
#pragma unroll
      for (int j = 0; j < 4; ++j)
        C[(size_t)(row0 + j) * N_DIM + col] = v[j] * s + bv;
    }
  }
}

extern "C" void kernel_launch(void* const* d_in, const int* in_sizes, int n_in,
                              void* d_out, int out_size, void* d_ws, size_t ws_size,
                              hipStream_t stream) {
  const float* x      = (const float*)d_in[0];
  const int*   codes  = (const int*)d_in[1];
  const float* cb     = (const float*)d_in[2];
  const float* scales = (const float*)d_in[3];
  const float* bias   = (const float*)d_in[4];
  float* out = (float*)d_out;

  // workspace: xb (bf16 x, 64 MB) | wb (bf16 W, 32 MB)
  unsigned short* xb = (unsigned short*)d_ws;
  unsigned short* wb = (unsigned short*)((char*)d_ws + (size_t)M_DIM * K_DIM * 2);

  cvt_x_kernel<<<4096, 256, 0, stream>>>(x, xb, (M_DIM * K_DIM) / 8);
  dequant_kernel<<<(NOG * NIG) / 256, 256, 0, stream>>>(codes, cb, wb);
  gemm_kernel<<<dim3((M_DIM / 128) * (N_DIM / 128)), 256, 0, stream>>>(xb, wb, scales, bias, out);
}

// Round 2
// 271.215 us; speedup vs baseline: 1.3761x; 1.3761x over previous
//
#include <hip/hip_runtime.h>
#include <hip/hip_bf16.h>

// QuantizedLinear: out[8192,4096] = x[8192,4096] @ W^T + bias
//   W[n,k] = codebooks[codes[n, k/8]][k%8] * scales[n]  (NCB=1; scale folded into epilogue)
// Pipeline: cvt x->bf16, dequant W->bf16 [N][K], then 256x256 8-phase MFMA GEMM
// (T1 XCD swizzle + T2 st_16x32 LDS swizzle + T3/T4 counted vmcnt + T5 setprio).
#define M_DIM 8192
#define N_DIM 4096
#define K_DIM 4096
#define NOG 4096
#define NIG 512

typedef __bf16 bf16x8 __attribute__((ext_vector_type(8)));
typedef float f32x4 __attribute__((ext_vector_type(4)));
typedef short short8 __attribute__((ext_vector_type(8)));

typedef const __attribute__((address_space(1))) void* as1_cvoid_p;
typedef __attribute__((address_space(3))) void* as3_void_p;

__device__ __forceinline__ unsigned short f2bf(float f) {
  union { float f; unsigned u; } c; c.f = f;
  unsigned u = c.u;
  return (unsigned short)((u + 0x7fffu + ((u >> 16) & 1u)) >> 16);
}

// ---- Kernel 1: x f32 -> bf16
__global__ __launch_bounds__(256) void cvt_x_kernel(const float* __restrict__ x,
                                                    unsigned short* __restrict__ xb,
                                                    int n8) {
  int i = blockIdx.x * blockDim.x + threadIdx.x;
  int stride = gridDim.x * blockDim.x;
  for (; i < n8; i += stride) {
    const float4* p = (const float4*)(x) + (size_t)i * 2;
    float4 a = p[0], b = p[1];
    short8 o;
    o[0] = (short)f2bf(a.x); o[1] = (short)f2bf(a.y);
    o[2] = (short)f2bf(a.z); o[3] = (short)f2bf(a.w);
    o[4] = (short)f2bf(b.x); o[5] = (short)f2bf(b.y);
    o[6] = (short)f2bf(b.z); o[7] = (short)f2bf(b.w);
    ((short8*)xb)[i] = o;
  }
}

// ---- Kernel 2: gather-dequant -> bf16 W [N][K]
__global__ __launch_bounds__(256) void dequant_kernel(const int* __restrict__ codes,
                                                      const float* __restrict__ cb,
                                                      unsigned short* __restrict__ wb) {
  int idx = blockIdx.x * blockDim.x + threadIdx.x;
  int code = codes[idx];
  const float4* p = (const float4*)(cb + (size_t)code * 8);
  float4 a = p[0], b = p[1];
  short8 o;
  o[0] = (short)f2bf(a.x); o[1] = (short)f2bf(a.y);
  o[2] = (short)f2bf(a.z); o[3] = (short)f2bf(a.w);
  o[4] = (short)f2bf(b.x); o[5] = (short)f2bf(b.y);
  o[6] = (short)f2bf(b.z); o[7] = (short)f2bf(b.w);
  ((short8*)wb)[idx] = o;
}

// ---- Kernel 3: 256x256 8-phase GEMM, BK=64, 8 waves (2Mx4N), 128 KiB LDS (2 slots),
// st_16x32 swizzle (two 32-col panels, 64B rows, byte ^= ((byte>>9)&1)<<5).
// LDS map per slot: A at 0 (32 KiB: panel*16384 + r*64 + col), B at 65536.
// Half-tiles: A-h = rows (r&64)?1:0 ; B-h = rows (r&32)?1:0.
// Group (tile t, 4 phases): reads ph0:{A-lo,B-lo} ph1:{B-hi} ph2:{A-hi};
// stages ph0:A-hi(t+1) ph1:A-lo(t+2) ph2:B-lo(t+2) ph3:B-hi(t+2); vmcnt(6)@ph3.

#define BAR() __builtin_amdgcn_s_barrier()
#define WAITLGKM() asm volatile("s_waitcnt lgkmcnt(0)" ::: "memory")
#define PRIO1() __builtin_amdgcn_s_setprio(1)
#define PRIO0() __builtin_amdgcn_s_setprio(0)

#define STAGE_A(slot_, h_, kt_) do { \
  _Pragma("unroll") for (int i_ = 0; i_ < 2; ++i_) { \
    const unsigned short* src_ = Ag + (size_t)(sa_roff[i_] + (h_) * 64) * 4096 + (unsigned)((kt_) + sa_koff[i_]); \
    __builtin_amdgcn_global_load_lds((as1_cvoid_p)src_, \
      (as3_void_p)(smem + (slot_) * 32768 + sa_lds[i_] + (h_) * 4096), 16, 0, 0); \
  } } while (0)

#define STAGE_B(slot_, h_, kt_) do { \
  _Pragma("unroll") for (int i_ = 0; i_ < 2; ++i_) { \
    const unsigned short* src_ = Bg + (size_t)(sb_roff[i_] + (h_) * 32) * 4096 + (unsigned)((kt_) + sb_koff[i_]); \
    __builtin_amdgcn_global_load_lds((as1_cvoid_p)src_, \
      (as3_void_p)(smem + 65536 + (slot_) * 32768 + sb_lds[i_] + (h_) * 2048), 16, 0, 0); \
  } } while (0)

#define LDA(ma_, slot_) \
  _Pragma("unroll") for (int m_ = 0; m_ < 4; ++m_) \
  _Pragma("unroll") for (int kk_ = 0; kk_ < 2; ++kk_) \
    af[m_][kk_] = *(const bf16x8*)(smem + (slot_) * 32768 + aRd + ((ma_) * 4 + m_) * 1024 + kk_ * 16384);

#define LDB(n0_, dst_, slot_) \
  _Pragma("unroll") for (int n_ = 0; n_ < 2; ++n_) \
  _Pragma("unroll") for (int kk_ = 0; kk_ < 2; ++kk_) \
    dst_[n_][kk_] = *(const bf16x8*)(smem + (slot_) * 32768 + bRd + ((n0_) + n_) * 1024 + kk_ * 16384);

#define MM(m0_, nb_, bfr_) \
  _Pragma("unroll") for (int m_ = 0; m_ < 4; ++m_) \
  _Pragma("unroll") for (int n_ = 0; n_ < 2; ++n_) \
  _Pragma("unroll") for (int kk_ = 0; kk_ < 2; ++kk_) \
    acc[(m0_) + m_][(nb_) + n_] = __builtin_amdgcn_mfma_f32_16x16x32_bf16( \
        af[m_][kk_], bfr_[n_][kk_], acc[(m0_) + m_][(nb_) + n_], 0, 0, 0);

// MODE: 2=steady, 1=penultimate (only ph0 stage, vmcnt(0)), 0=last (no stage/vmcnt)
#define GROUP(SLOT_, MODE_, KT_) do { \
  /* phase 0 */ \
  LDA(0, SLOT_); LDB(0, bf0, SLOT_); \
  if ((MODE_) >= 1) STAGE_A((SLOT_) ^ 1, 1, (KT_) + 64); \
  BAR(); WAITLGKM(); PRIO1(); MM(0, 0, bf0); PRIO0(); BAR(); \
  /* phase 1 */ \
  LDB(2, bf1, SLOT_); \
  if ((MODE_) == 2) STAGE_A(SLOT_, 0, (KT_) + 128); \
  BAR(); WAITLGKM(); PRIO1(); MM(0, 2, bf1); PRIO0(); BAR(); \
  /* phase 2 */ \
  LDA(1, SLOT_); \
  if ((MODE_) == 2) STAGE_B(SLOT_, 0, (KT_) + 128); \
  BAR(); WAITLGKM(); PRIO1(); MM(4, 0, bf0); PRIO0(); BAR(); \
  /* phase 3 */ \
  if ((MODE_) == 2) STAGE_B(SLOT_, 1, (KT_) + 128); \
  if ((MODE_) == 2) { asm volatile("s_waitcnt vmcnt(6)" ::: "memory"); } \
  else if ((MODE_) == 1) { asm volatile("s_waitcnt vmcnt(0)" ::: "memory"); } \
  BAR(); PRIO1(); MM(4, 2, bf1); PRIO0(); BAR(); \
} while (0)

__global__ __launch_bounds__(512) void gemm8_kernel(
    const unsigned short* __restrict__ A,   // bf16 [M][K]
    const unsigned short* __restrict__ B,   // bf16 [N][K]
    const float* __restrict__ scales,
    const float* __restrict__ bias,
    float* __restrict__ C) {
  extern __shared__ char smem[];  // 131072 B

  // grid 512 = 32 bm x 16 bn; bijective XCD swizzle (512 % 8 == 0)
  const int bid = blockIdx.x;
  const int swz = (bid & 7) * 64 + (bid >> 3);
  const int bm = swz >> 4;
  const int bn = swz & 15;

  const int tid = threadIdx.x;
  const int w = tid >> 6;
  const int l = tid & 63;
  const int wr = w >> 2;    // 0..1
  const int wcol = w & 3;   // 0..3

  // ---- staging constants (linear LDS dest, inverse-swizzled global source)
  const int llog = l ^ (((l >> 5) & 1) << 1);
  int sa_roff[2], sa_koff[2], sa_lds[2];
  int sb_roff[2], sb_koff[2], sb_lds[2];
#pragma unroll
  for (int i = 0; i < 2; ++i) {
    int u = w * 2 + i;
    int panel = u >> 3;
    int rbA = (u >> 2) & 1, chA = u & 3;
    sa_roff[i] = rbA * 128 + chA * 16 + (llog >> 2);
    sa_koff[i] = panel * 32 + (llog & 3) * 8;
    sa_lds[i] = panel * 16384 + rbA * 8192 + chA * 1024;
    int bb = (u >> 1) & 3, hk = u & 1;
    sb_roff[i] = bb * 64 + hk * 16 + (llog >> 2);
    sb_koff[i] = panel * 32 + (llog & 3) * 8;
    sb_lds[i] = panel * 16384 + bb * 4096 + hk * 1024;
  }

  const unsigned short* Ag = A + (size_t)bm * 256 * 4096;
  const unsigned short* Bg = B + (size_t)bn * 256 * 4096;

  // ---- fragment read base addresses (swizzled)
  const int xr = ((l >> 4) * 16) ^ (((l >> 3) & 1) << 5);
  const int aRd = (wr * 128 + (l & 15)) * 64 + xr;
  const int bRd = 65536 + (wcol * 64 + (l & 15)) * 64 + xr;

  f32x4 acc[8][4];
#pragma unroll
  for (int m = 0; m < 8; ++m)
#pragma unroll
    for (int n = 0; n < 4; ++n) acc[m][n] = (f32x4){0.f, 0.f, 0.f, 0.f};

  bf16x8 af[4][2], bf0[2][2], bf1[2][2];

  // ---- prologue: tile0 {A0,A1,B0,B1}, vmcnt(4), tile1 {A0,B0,B1}, vmcnt(6)
  STAGE_A(0, 0, 0); STAGE_A(0, 1, 0); STAGE_B(0, 0, 0); STAGE_B(0, 1, 0);
  asm volatile("s_waitcnt vmcnt(4)" ::: "memory");
  STAGE_A(1, 0, 64); STAGE_B(1, 0, 64); STAGE_B(1, 1, 64);
  asm volatile("s_waitcnt vmcnt(6)" ::: "memory");
  BAR();

  // ---- main loop: 64 K-tiles; groups 0..61 steady, 62 penult, 63 last
  int kt = 0;
  for (int j = 0; j < 31; ++j) {
    GROUP(0, 2, kt);
    GROUP(1, 2, kt + 64);
    kt += 128;
  }
  GROUP(0, 1, kt);        // group 62 (stages A-hi of tile 63 @ kt+64=4032)
  GROUP(1, 0, kt + 64);   // group 63

  // ---- epilogue: scale + bias, fp32 store
  const int row0 = bm * 256 + wr * 128 + ((l >> 4) << 2);
  const int col0 = bn * 256 + wcol * 64 + (l & 15);
#pragma unroll
  for (int n = 0; n < 4; ++n) {
    const int col = col0 + n * 16;
    const float s = scales[col];
    const float bv = bias[col];
#pragma unroll
    for (int m = 0; m < 8; ++m) {
      f32x4 v = acc[m][n];
      const int r = row0 + m * 16;
#pragma unroll
      for (int j = 0; j < 4; ++j)
        C[(size_t)(r + j) * 4096 + col] = v[j] * s + bv;
    }
  }
}

extern "C" void kernel_launch(void* const* d_in, const int* in_sizes, int n_in,
                              void* d_out, int out_size, void* d_ws, size_t ws_size,
                              hipStream_t stream) {
  const float* x = (const float*)d_in[0];
  const int* codes = (const int*)d_in[1];
  const float* cb = (const float*)d_in[2];
  const float* scales = (const float*)d_in[3];
  const float* bias = (const float*)d_in[4];
  float* out = (float*)d_out;

  unsigned short* xb = (unsigned short*)d_ws;
  unsigned short* wb = (unsigned short*)((char*)d_ws + (size_t)M_DIM * K_DIM * 2);

  hipFuncSetAttribute((const void*)gemm8_kernel,
                      hipFuncAttributeMaxDynamicSharedMemorySize, 131072);

  cvt_x_kernel<<<4096, 256, 0, stream>>>(x, xb, (M_DIM * K_DIM) / 8);
  dequant_kernel<<<(NOG * NIG) / 256, 256, 0, stream>>>(codes, cb, wb);
  gemm8_kernel<<<dim3((M_DIM / 256) * (N_DIM / 256)), 512, 131072, stream>>>(
      xb, wb, scales, bias, out);
}

// Round 3
// 262.850 us; speedup vs baseline: 1.4199x; 1.0318x over previous
//
#include <hip/hip_runtime.h>
#include <hip/hip_bf16.h>

// QuantizedLinear: out[8192,4096] = x[8192,4096] @ W^T + bias
//   W[n,k] = codebooks[codes[n, k/8]][k%8] * scales[n]  (NCB=1; scale folded into epilogue)
// Pipeline: cvt x->bf16, dequant W->bf16 [N][K], then 256x256 MFMA GEMM with
// 4-window overlapped schedule: B-frag prefetch one window ahead, A-frag
// quarter-split with counted lgkmcnt, 3 barriers + derived vmcnt per group.
#define M_DIM 8192
#define N_DIM 4096
#define K_DIM 4096
#define NOG 4096
#define NIG 512

typedef __bf16 bf16x8 __attribute__((ext_vector_type(8)));
typedef float f32x4 __attribute__((ext_vector_type(4)));
typedef short short8 __attribute__((ext_vector_type(8)));

typedef const __attribute__((address_space(1))) void* as1_cvoid_p;
typedef __attribute__((address_space(3))) void* as3_void_p;

__device__ __forceinline__ unsigned short f2bf(float f) {
  union { float f; unsigned u; } c; c.f = f;
  unsigned u = c.u;
  return (unsigned short)((u + 0x7fffu + ((u >> 16) & 1u)) >> 16);
}

// ---- Kernel 1: x f32 -> bf16
__global__ __launch_bounds__(256) void cvt_x_kernel(const float* __restrict__ x,
                                                    unsigned short* __restrict__ xb,
                                                    int n8) {
  int i = blockIdx.x * blockDim.x + threadIdx.x;
  int stride = gridDim.x * blockDim.x;
  for (; i < n8; i += stride) {
    const float4* p = (const float4*)(x) + (size_t)i * 2;
    float4 a = p[0], b = p[1];
    short8 o;
    o[0] = (short)f2bf(a.x); o[1] = (short)f2bf(a.y);
    o[2] = (short)f2bf(a.z); o[3] = (short)f2bf(a.w);
    o[4] = (short)f2bf(b.x); o[5] = (short)f2bf(b.y);
    o[6] = (short)f2bf(b.z); o[7] = (short)f2bf(b.w);
    ((short8*)xb)[i] = o;
  }
}

// ---- Kernel 2: gather-dequant -> bf16 W [N][K]
__global__ __launch_bounds__(256) void dequant_kernel(const int* __restrict__ codes,
                                                      const float* __restrict__ cb,
                                                      unsigned short* __restrict__ wb) {
  int idx = blockIdx.x * blockDim.x + threadIdx.x;
  int code = codes[idx];
  const float4* p = (const float4*)(cb + (size_t)code * 8);
  float4 a = p[0], b = p[1];
  short8 o;
  o[0] = (short)f2bf(a.x); o[1] = (short)f2bf(a.y);
  o[2] = (short)f2bf(a.z); o[3] = (short)f2bf(a.w);
  o[4] = (short)f2bf(b.x); o[5] = (short)f2bf(b.y);
  o[6] = (short)f2bf(b.z); o[7] = (short)f2bf(b.w);
  ((short8*)wb)[idx] = o;
}

// ---- Kernel 3: 256x256 GEMM, BK=64, 8 waves (2Mx4N), 128 KiB LDS (2 slots),
// st_16x32 swizzle. Stage schedule per group g (slot s = g&1):
//   W0: AH(g+1)->s^1   W1: AL(g+2)->s   W2: BL(g+2)->s   W3: BH(g+2)->s
// Waits: vmcnt(8)@W0-end, vmcnt(8)@W1-end, vmcnt(6)@W2-end; barriers end-W0/W1/W2.
// Reads: W0: aL(q1,q2)+bH [12]; W2: aH(q1,q2) [8]; W3: bL(g+1) [4]. B single-buffered.

#define BAR() __builtin_amdgcn_s_barrier()
#define SB() __builtin_amdgcn_sched_barrier(0)
#define PRIO1() __builtin_amdgcn_s_setprio(1)
#define PRIO0() __builtin_amdgcn_s_setprio(0)
#define LGKM(N_) asm volatile("s_waitcnt lgkmcnt(" #N_ ")" ::: "memory")
#define VMC(N_) asm volatile("s_waitcnt vmcnt(" #N_ ")" ::: "memory")

#define STAGE_A(slot_, h_, kt_) do { \
  _Pragma("unroll") for (int i_ = 0; i_ < 2; ++i_) { \
    const unsigned short* src_ = Ag + (size_t)(sa_roff[i_] + (h_) * 64) * 4096 + (unsigned)((kt_) + sa_koff[i_]); \
    __builtin_amdgcn_global_load_lds((as1_cvoid_p)src_, \
      (as3_void_p)(smem + (slot_) * 32768 + sa_lds[i_] + (h_) * 4096), 16, 0, 0); \
  } } while (0)

#define STAGE_B(slot_, h_, kt_) do { \
  _Pragma("unroll") for (int i_ = 0; i_ < 2; ++i_) { \
    const unsigned short* src_ = Bg + (size_t)(sb_roff[i_] + (h_) * 32) * 4096 + (unsigned)((kt_) + sb_koff[i_]); \
    __builtin_amdgcn_global_load_lds((as1_cvoid_p)src_, \
      (as3_void_p)(smem + 65536 + (slot_) * 32768 + sb_lds[i_] + (h_) * 2048), 16, 0, 0); \
  } } while (0)

// quarter A-fragment read: q_=0 -> af[0..1], q_=1 -> af[2..3]; ma_ = A half (0/1)
#define LDA_Q(q_, ma_, slot_) \
  _Pragma("unroll") for (int j_ = 0; j_ < 2; ++j_) \
  _Pragma("unroll") for (int kk_ = 0; kk_ < 2; ++kk_) \
    af[(q_) * 2 + j_][kk_] = *(const bf16x8*)(smem + (slot_) * 32768 + aRd + ((ma_) * 4 + (q_) * 2 + j_) * 1024 + kk_ * 16384);

#define LDB(n0_, dst_, slot_) \
  _Pragma("unroll") for (int n_ = 0; n_ < 2; ++n_) \
  _Pragma("unroll") for (int kk_ = 0; kk_ < 2; ++kk_) \
    dst_[n_][kk_] = *(const bf16x8*)(smem + (slot_) * 32768 + bRd + ((n0_) + n_) * 1024 + kk_ * 16384);

// 8 MFMAs: acc rows base_+q_*2..+1, cols nb_..nb_+1
#define MM_Q(base_, q_, nb_, bfr_) \
  _Pragma("unroll") for (int j_ = 0; j_ < 2; ++j_) \
  _Pragma("unroll") for (int n_ = 0; n_ < 2; ++n_) \
  _Pragma("unroll") for (int kk_ = 0; kk_ < 2; ++kk_) \
    acc[(base_) + (q_) * 2 + j_][(nb_) + n_] = __builtin_amdgcn_mfma_f32_16x16x32_bf16( \
        af[(q_) * 2 + j_][kk_], bfr_[n_][kk_], acc[(base_) + (q_) * 2 + j_][(nb_) + n_], 0, 0, 0);

// MODE: 2=steady, 1=g=62 (stage AH only, vmcnt {8,6,2}), 0=g=63 (no stage, vmcnt(0)@W0)
#define GROUP(SLOT_, MODE_, KT_) do { \
  /* W0: reads aL q1,q2 + bH; stage AH(t+1) */ \
  LDA_Q(0, 0, SLOT_); LDA_Q(1, 0, SLOT_); LDB(2, bf1, SLOT_); \
  if ((MODE_) >= 1) STAGE_A((SLOT_) ^ 1, 1, (KT_) + 64); \
  LGKM(8); SB(); PRIO1(); MM_Q(0, 0, 0, bf0); \
  LGKM(4); SB(); MM_Q(0, 1, 0, bf0); PRIO0(); \
  if ((MODE_) >= 1) { VMC(8); } else { VMC(0); } \
  BAR(); \
  /* W1: 16 mfma on aL x bH; stage AL(t+2) */ \
  if ((MODE_) == 2) STAGE_A(SLOT_, 0, (KT_) + 128); \
  PRIO1(); MM_Q(0, 0, 2, bf1); MM_Q(0, 1, 2, bf1); PRIO0(); \
  if ((MODE_) == 2) { VMC(8); } else if ((MODE_) == 1) { VMC(6); } \
  BAR(); \
  /* W2: reads aH q1,q2; stage BL(t+2) */ \
  LDA_Q(0, 1, SLOT_); LDA_Q(1, 1, SLOT_); \
  if ((MODE_) == 2) STAGE_B(SLOT_, 0, (KT_) + 128); \
  LGKM(4); SB(); PRIO1(); MM_Q(4, 0, 0, bf0); \
  LGKM(0); SB(); MM_Q(4, 1, 0, bf0); PRIO0(); \
  if ((MODE_) == 2) { VMC(6); } else if ((MODE_) == 1) { VMC(2); } \
  BAR(); \
  /* W3: read bL(t+1); stage BH(t+2); 16 mfma; no barrier (flows into W0) */ \
  if ((MODE_) >= 1) { LDB(0, bf0, (SLOT_) ^ 1); } \
  if ((MODE_) == 2) STAGE_B(SLOT_, 1, (KT_) + 128); \
  PRIO1(); MM_Q(4, 0, 2, bf1); MM_Q(4, 1, 2, bf1); PRIO0(); \
} while (0)

__global__ __launch_bounds__(512) void gemm8_kernel(
    const unsigned short* __restrict__ A,   // bf16 [M][K]
    const unsigned short* __restrict__ B,   // bf16 [N][K]
    const float* __restrict__ scales,
    const float* __restrict__ bias,
    float* __restrict__ C) {
  extern __shared__ char smem[];  // 131072 B

  // grid 512 = 32 bm x 16 bn; bijective XCD swizzle (512 % 8 == 0)
  const int bid = blockIdx.x;
  const int swz = (bid & 7) * 64 + (bid >> 3);
  const int bm = swz >> 4;
  const int bn = swz & 15;

  const int tid = threadIdx.x;
  const int w = tid >> 6;
  const int l = tid & 63;
  const int wr = w >> 2;    // 0..1
  const int wcol = w & 3;   // 0..3

  // ---- staging constants (linear LDS dest, inverse-swizzled global source)
  const int llog = l ^ (((l >> 5) & 1) << 1);
  int sa_roff[2], sa_koff[2], sa_lds[2];
  int sb_roff[2], sb_koff[2], sb_lds[2];
#pragma unroll
  for (int i = 0; i < 2; ++i) {
    int u = w * 2 + i;
    int panel = u >> 3;
    int rbA = (u >> 2) & 1, chA = u & 3;
    sa_roff[i] = rbA * 128 + chA * 16 + (llog >> 2);
    sa_koff[i] = panel * 32 + (llog & 3) * 8;
    sa_lds[i] = panel * 16384 + rbA * 8192 + chA * 1024;
    int bb = (u >> 1) & 3, hk = u & 1;
    sb_roff[i] = bb * 64 + hk * 16 + (llog >> 2);
    sb_koff[i] = panel * 32 + (llog & 3) * 8;
    sb_lds[i] = panel * 16384 + bb * 4096 + hk * 1024;
  }

  const unsigned short* Ag = A + (size_t)bm * 256 * 4096;
  const unsigned short* Bg = B + (size_t)bn * 256 * 4096;

  // ---- fragment read base addresses (swizzled)
  const int xr = ((l >> 4) * 16) ^ (((l >> 3) & 1) << 5);
  const int aRd = (wr * 128 + (l & 15)) * 64 + xr;
  const int bRd = 65536 + (wcol * 64 + (l & 15)) * 64 + xr;

  f32x4 acc[8][4];
#pragma unroll
  for (int m = 0; m < 8; ++m)
#pragma unroll
    for (int n = 0; n < 4; ++n) acc[m][n] = (f32x4){0.f, 0.f, 0.f, 0.f};

  bf16x8 af[4][2], bf0[2][2], bf1[2][2];

  // ---- prologue: stage AL0,BL0,BH0, AH0, AL1,BL1,BH1 (7 half-tiles, 14 loads)
  STAGE_A(0, 0, 0); STAGE_B(0, 0, 0); STAGE_B(0, 1, 0);
  STAGE_A(0, 1, 0);
  STAGE_A(1, 0, 64); STAGE_B(1, 0, 64); STAGE_B(1, 1, 64);
  VMC(8);   // drains AL0,BL0,BH0; keeps {AH0, AL1, BL1, BH1}
  BAR();
  LDB(0, bf0, 0);   // bL(0): steady-state entry expects these 4 reads in flight

  // ---- main loop: 64 K-tiles; groups 0..61 steady, 62 penult, 63 last
  int kt = 0;
  for (int j = 0; j < 31; ++j) {
    GROUP(0, 2, kt);
    GROUP(1, 2, kt + 64);
    kt += 128;
  }
  GROUP(0, 1, kt);        // g=62: stages AH(63) only
  GROUP(1, 0, kt + 64);   // g=63

  // ---- epilogue: scale + bias, fp32 store
  const int row0 = bm * 256 + wr * 128 + ((l >> 4) << 2);
  const int col0 = bn * 256 + wcol * 64 + (l & 15);
#pragma unroll
  for (int n = 0; n < 4; ++n) {
    const int col = col0 + n * 16;
    const float s = scales[col];
    const float bv = bias[col];
#pragma unroll
    for (int m = 0; m < 8; ++m) {
      f32x4 v = acc[m][n];
      const int r = row0 + m * 16;
#pragma unroll
      for (int j = 0; j < 4; ++j)
        C[(size_t)(r + j) * 4096 + col] = v[j] * s + bv;
    }
  }
}

extern "C" void kernel_launch(void* const* d_in, const int* in_sizes, int n_in,
                              void* d_out, int out_size, void* d_ws, size_t ws_size,
                              hipStream_t stream) {
  const float* x = (const float*)d_in[0];
  const int* codes = (const int*)d_in[1];
  const float* cb = (const float*)d_in[2];
  const float* scales = (const float*)d_in[3];
  const float* bias = (const float*)d_in[4];
  float* out = (float*)d_out;

  unsigned short* xb = (unsigned short*)d_ws;
  unsigned short* wb = (unsigned short*)((char*)d_ws + (size_t)M_DIM * K_DIM * 2);

  hipFuncSetAttribute((const void*)gemm8_kernel,
                      hipFuncAttributeMaxDynamicSharedMemorySize, 131072);

  cvt_x_kernel<<<4096, 256, 0, stream>>>(x, xb, (M_DIM * K_DIM) / 8);
  dequant_kernel<<<(NOG * NIG) / 256, 256, 0, stream>>>(codes, cb, wb);
  gemm8_kernel<<<dim3((M_DIM / 256) * (N_DIM / 256)), 512, 131072, stream>>>(
      xb, wb, scales, bias, out);
}

// Round 4
// 258.481 us; speedup vs baseline: 1.4439x; 1.0169x over previous
//
#include <hip/hip_runtime.h>
#include <hip/hip_bf16.h>

// QuantizedLinear: out[8192,4096] = x[8192,4096] @ W^T + bias
//   W[n,k] = codebooks[codes[n, k/8]][k%8] * scales[n]  (NCB=1; scale folded into epilogue)
// Pipeline: cvt x->bf16, dequant W->bf16 [N][K], then 256x256 MFMA GEMM.
// Round-4 schedule: ALL ds_reads issue one window early (aH at W1-end, next-tile
// {aL,bL,bH} at W3-end) into the same frag regs (WAR after last MFMA use), so every
// window's MFMA cluster starts on counted-lgkm against already-issued reads.
// Only 2 vmcnt waits per group (W0-end 8, W2-end 6), 3 barriers.
#define M_DIM 8192
#define N_DIM 4096
#define K_DIM 4096
#define NOG 4096
#define NIG 512

typedef __bf16 bf16x8 __attribute__((ext_vector_type(8)));
typedef float f32x4 __attribute__((ext_vector_type(4)));
typedef short short8 __attribute__((ext_vector_type(8)));

typedef const __attribute__((address_space(1))) void* as1_cvoid_p;
typedef __attribute__((address_space(3))) void* as3_void_p;

__device__ __forceinline__ unsigned short f2bf(float f) {
  union { float f; unsigned u; } c; c.f = f;
  unsigned u = c.u;
  return (unsigned short)((u + 0x7fffu + ((u >> 16) & 1u)) >> 16);
}

// ---- Kernel 1: x f32 -> bf16
__global__ __launch_bounds__(256) void cvt_x_kernel(const float* __restrict__ x,
                                                    unsigned short* __restrict__ xb,
                                                    int n8) {
  int i = blockIdx.x * blockDim.x + threadIdx.x;
  int stride = gridDim.x * blockDim.x;
  for (; i < n8; i += stride) {
    const float4* p = (const float4*)(x) + (size_t)i * 2;
    float4 a = p[0], b = p[1];
    short8 o;
    o[0] = (short)f2bf(a.x); o[1] = (short)f2bf(a.y);
    o[2] = (short)f2bf(a.z); o[3] = (short)f2bf(a.w);
    o[4] = (short)f2bf(b.x); o[5] = (short)f2bf(b.y);
    o[6] = (short)f2bf(b.z); o[7] = (short)f2bf(b.w);
    ((short8*)xb)[i] = o;
  }
}

// ---- Kernel 2: gather-dequant -> bf16 W [N][K]
__global__ __launch_bounds__(256) void dequant_kernel(const int* __restrict__ codes,
                                                      const float* __restrict__ cb,
                                                      unsigned short* __restrict__ wb) {
  int idx = blockIdx.x * blockDim.x + threadIdx.x;
  int code = codes[idx];
  const float4* p = (const float4*)(cb + (size_t)code * 8);
  float4 a = p[0], b = p[1];
  short8 o;
  o[0] = (short)f2bf(a.x); o[1] = (short)f2bf(a.y);
  o[2] = (short)f2bf(a.z); o[3] = (short)f2bf(a.w);
  o[4] = (short)f2bf(b.x); o[5] = (short)f2bf(b.y);
  o[6] = (short)f2bf(b.z); o[7] = (short)f2bf(b.w);
  ((short8*)wb)[idx] = o;
}

// ---- Kernel 3: 256x256 GEMM, BK=64, 8 waves (2Mx4N), 128 KiB LDS (2 slots),
// st_16x32 swizzle. Stages: W0:AH(t+1)->s^1  W1:AL(t+2)->s  W2:BL(t+2)->s  W3:BH(t+2)->s.
// Reads (one window early): W1-end: aH(t)[8]; W3-end: aL(t+1)[4]+bL(t+1)[4]+aL q2[4]+bH(t+1)[4].
// Waits: VMC(8)@W0-end, VMC(6)@W2-end; barriers end-W0/W1/W2; LGKM 8/4 @W0, 0 @W1, 4/0 @W2.

#define BAR() __builtin_amdgcn_s_barrier()
#define SB() __builtin_amdgcn_sched_barrier(0)
#define PRIO1() __builtin_amdgcn_s_setprio(1)
#define PRIO0() __builtin_amdgcn_s_setprio(0)
#define LGKM(N_) asm volatile("s_waitcnt lgkmcnt(" #N_ ")" ::: "memory")
#define VMC(N_) asm volatile("s_waitcnt vmcnt(" #N_ ")" ::: "memory")

#define STAGE_A(slot_, h_, kt_) do { \
  _Pragma("unroll") for (int i_ = 0; i_ < 2; ++i_) { \
    const unsigned short* src_ = Ag + (size_t)(sa_roff[i_] + (h_) * 64) * 4096 + (unsigned)((kt_) + sa_koff[i_]); \
    __builtin_amdgcn_global_load_lds((as1_cvoid_p)src_, \
      (as3_void_p)(smem + (slot_) * 32768 + sa_lds[i_] + (h_) * 4096), 16, 0, 0); \
  } } while (0)

#define STAGE_B(slot_, h_, kt_) do { \
  _Pragma("unroll") for (int i_ = 0; i_ < 2; ++i_) { \
    const unsigned short* src_ = Bg + (size_t)(sb_roff[i_] + (h_) * 32) * 4096 + (unsigned)((kt_) + sb_koff[i_]); \
    __builtin_amdgcn_global_load_lds((as1_cvoid_p)src_, \
      (as3_void_p)(smem + 65536 + (slot_) * 32768 + sb_lds[i_] + (h_) * 2048), 16, 0, 0); \
  } } while (0)

// quarter A-fragment read: q_=0 -> af[0..1], q_=1 -> af[2..3]; ma_ = A half (0/1)
#define LDA_Q(q_, ma_, slot_) \
  _Pragma("unroll") for (int j_ = 0; j_ < 2; ++j_) \
  _Pragma("unroll") for (int kk_ = 0; kk_ < 2; ++kk_) \
    af[(q_) * 2 + j_][kk_] = *(const bf16x8*)(smem + (slot_) * 32768 + aRd + ((ma_) * 4 + (q_) * 2 + j_) * 1024 + kk_ * 16384);

#define LDB(n0_, dst_, slot_) \
  _Pragma("unroll") for (int n_ = 0; n_ < 2; ++n_) \
  _Pragma("unroll") for (int kk_ = 0; kk_ < 2; ++kk_) \
    dst_[n_][kk_] = *(const bf16x8*)(smem + (slot_) * 32768 + bRd + ((n0_) + n_) * 1024 + kk_ * 16384);

// 8 MFMAs: acc rows base_+q_*2..+1, cols nb_..nb_+1
#define MM_Q(base_, q_, nb_, bfr_) \
  _Pragma("unroll") for (int j_ = 0; j_ < 2; ++j_) \
  _Pragma("unroll") for (int n_ = 0; n_ < 2; ++n_) \
  _Pragma("unroll") for (int kk_ = 0; kk_ < 2; ++kk_) \
    acc[(base_) + (q_) * 2 + j_][(nb_) + n_] = __builtin_amdgcn_mfma_f32_16x16x32_bf16( \
        af[(q_) * 2 + j_][kk_], bfr_[n_][kk_], acc[(base_) + (q_) * 2 + j_][(nb_) + n_], 0, 0, 0);

// next-tile register refill: 16 ds_reads in pinned order aLq1, bL, aLq2, bH
#define REFILL_NEXT(slotn_) do { \
  LDA_Q(0, 0, slotn_); SB(); LDB(0, bf0, slotn_); SB(); \
  LDA_Q(1, 0, slotn_); SB(); LDB(2, bf1, slotn_); SB(); \
} while (0)

// MODE: 2=steady, 1=g=62 (stage AH only; VMC {8,-,2}), 0=g=63 (VMC(0)@W0; no refill)
#define GROUP(SLOT_, MODE_, KT_) do { \
  /* W0: MFMA aL x bL; stage AH(t+1) */ \
  if ((MODE_) >= 1) STAGE_A((SLOT_) ^ 1, 1, (KT_) + 64); \
  LGKM(8); SB(); PRIO1(); MM_Q(0, 0, 0, bf0); \
  LGKM(4); SB(); MM_Q(0, 1, 0, bf0); PRIO0(); \
  if ((MODE_) >= 1) { VMC(8); } else { VMC(0); } \
  BAR(); \
  /* W1: MFMA aL x bH; stage AL(t+2); refill af <- aH(t) at end */ \
  if ((MODE_) == 2) STAGE_A(SLOT_, 0, (KT_) + 128); \
  LGKM(0); SB(); PRIO1(); MM_Q(0, 0, 2, bf1); MM_Q(0, 1, 2, bf1); PRIO0(); \
  LDA_Q(0, 1, SLOT_); SB(); LDA_Q(1, 1, SLOT_); SB(); \
  BAR(); \
  /* W2: MFMA aH x bL; stage BL(t+2) */ \
  if ((MODE_) == 2) STAGE_B(SLOT_, 0, (KT_) + 128); \
  LGKM(4); SB(); PRIO1(); MM_Q(4, 0, 0, bf0); \
  LGKM(0); SB(); MM_Q(4, 1, 0, bf0); PRIO0(); \
  if ((MODE_) == 2) { VMC(6); } else if ((MODE_) == 1) { VMC(2); } \
  BAR(); \
  /* W3: MFMA aH x bH; stage BH(t+2); refill next-tile frags at end */ \
  if ((MODE_) == 2) STAGE_B(SLOT_, 1, (KT_) + 128); \
  PRIO1(); MM_Q(4, 0, 2, bf1); MM_Q(4, 1, 2, bf1); PRIO0(); \
  if ((MODE_) >= 1) REFILL_NEXT((SLOT_) ^ 1); \
} while (0)

__global__ __launch_bounds__(512) void gemm8_kernel(
    const unsigned short* __restrict__ A,   // bf16 [M][K]
    const unsigned short* __restrict__ B,   // bf16 [N][K]
    const float* __restrict__ scales,
    const float* __restrict__ bias,
    float* __restrict__ C) {
  extern __shared__ char smem[];  // 131072 B

  // grid 512 = 32 bm x 16 bn; bijective XCD swizzle (512 % 8 == 0)
  const int bid = blockIdx.x;
  const int swz = (bid & 7) * 64 + (bid >> 3);
  const int bm = swz >> 4;
  const int bn = swz & 15;

  const int tid = threadIdx.x;
  const int w = tid >> 6;
  const int l = tid & 63;
  const int wr = w >> 2;    // 0..1
  const int wcol = w & 3;   // 0..3

  // ---- staging constants (linear LDS dest, inverse-swizzled global source)
  const int llog = l ^ (((l >> 5) & 1) << 1);
  int sa_roff[2], sa_koff[2], sa_lds[2];
  int sb_roff[2], sb_koff[2], sb_lds[2];
#pragma unroll
  for (int i = 0; i < 2; ++i) {
    int u = w * 2 + i;
    int panel = u >> 3;
    int rbA = (u >> 2) & 1, chA = u & 3;
    sa_roff[i] = rbA * 128 + chA * 16 + (llog >> 2);
    sa_koff[i] = panel * 32 + (llog & 3) * 8;
    sa_lds[i] = panel * 16384 + rbA * 8192 + chA * 1024;
    int bb = (u >> 1) & 3, hk = u & 1;
    sb_roff[i] = bb * 64 + hk * 16 + (llog >> 2);
    sb_koff[i] = panel * 32 + (llog & 3) * 8;
    sb_lds[i] = panel * 16384 + bb * 4096 + hk * 1024;
  }

  const unsigned short* Ag = A + (size_t)bm * 256 * 4096;
  const unsigned short* Bg = B + (size_t)bn * 256 * 4096;

  // ---- fragment read base addresses (swizzled)
  const int xr = ((l >> 4) * 16) ^ (((l >> 3) & 1) << 5);
  const int aRd = (wr * 128 + (l & 15)) * 64 + xr;
  const int bRd = 65536 + (wcol * 64 + (l & 15)) * 64 + xr;

  f32x4 acc[8][4];
#pragma unroll
  for (int m = 0; m < 8; ++m)
#pragma unroll
    for (int n = 0; n < 4; ++n) acc[m][n] = (f32x4){0.f, 0.f, 0.f, 0.f};

  bf16x8 af[4][2], bf0[2][2], bf1[2][2];

  // ---- prologue: stage AL0,BL0,BH0 | AH0 | AL1,BL1,BH1; drain first 3; prime frags
  STAGE_A(0, 0, 0); STAGE_B(0, 0, 0); STAGE_B(0, 1, 0);
  STAGE_A(0, 1, 0);
  STAGE_A(1, 0, 64); STAGE_B(1, 0, 64); STAGE_B(1, 1, 64);
  VMC(8);   // 14 outstanding -> keep 8 newest {AH0, AL1, BL1, BH1}
  BAR();
  REFILL_NEXT(0);   // aL0 q1, bL0, aL0 q2, bH0 (16 reads in flight, steady invariant)

  // ---- main loop: 64 K-tiles; groups 0..61 steady, 62 penult, 63 last
  int kt = 0;
  for (int j = 0; j < 31; ++j) {
    GROUP(0, 2, kt);
    GROUP(1, 2, kt + 64);
    kt += 128;
  }
  GROUP(0, 1, kt);        // g=62: stages AH(63) only
  GROUP(1, 0, kt + 64);   // g=63

  // ---- epilogue: scale + bias, fp32 store
  const int row0 = bm * 256 + wr * 128 + ((l >> 4) << 2);
  const int col0 = bn * 256 + wcol * 64 + (l & 15);
#pragma unroll
  for (int n = 0; n < 4; ++n) {
    const int col = col0 + n * 16;
    const float s = scales[col];
    const float bv = bias[col];
#pragma unroll
    for (int m = 0; m < 8; ++m) {
      f32x4 v = acc[m][n];
      const int r = row0 + m * 16;
#pragma unroll
      for (int j = 0; j < 4; ++j)
        C[(size_t)(r + j) * 4096 + col] = v[j] * s + bv;
    }
  }
}

extern "C" void kernel_launch(void* const* d_in, const int* in_sizes, int n_in,
                              void* d_out, int out_size, void* d_ws, size_t ws_size,
                              hipStream_t stream) {
  const float* x = (const float*)d_in[0];
  const int* codes = (const int*)d_in[1];
  const float* cb = (const float*)d_in[2];
  const float* scales = (const float*)d_in[3];
  const float* bias = (const float*)d_in[4];
  float* out = (float*)d_out;

  unsigned short* xb = (unsigned short*)d_ws;
  unsigned short* wb = (unsigned short*)((char*)d_ws + (size_t)M_DIM * K_DIM * 2);

  hipFuncSetAttribute((const void*)gemm8_kernel,
                      hipFuncAttributeMaxDynamicSharedMemorySize, 131072);

  cvt_x_kernel<<<4096, 256, 0, stream>>>(x, xb, (M_DIM * K_DIM) / 8);
  dequant_kernel<<<(NOG * NIG) / 256, 256, 0, stream>>>(codes, cb, wb);
  gemm8_kernel<<<dim3((M_DIM / 256) * (N_DIM / 256)), 512, 131072, stream>>>(
      xb, wb, scales, bias, out);
}